// Round 1
// baseline (38.586 us; speedup 1.0000x reference)
//
#include <hip/hip_runtime.h>

// VolumeDCTPatchLayer: per-patch 6x6 2D DCT over (H,W), independent along B,C,D.
// x: (4, 8, 96, 96, 96) f32, contiguous, D innermost.
// out[b,c, n*6+a, m*6+u, d] = sum_{i,j} M[a][i]*M[u][j] * x[b,c, n*6+i, m*6+j, d]

#define BATCH 4
#define CH    8
#define HH    96
#define WW    96
#define DD    96
#define NH    16
#define NW    16

__global__ __launch_bounds__(256) void
dct_patch_kernel(const float* __restrict__ x, float* __restrict__ out) {
    // One thread = one (b,c,n,m, d-pair). 48 d-pairs per patch.
    constexpr int ITEMS = BATCH * CH * NH * NW * (DD / 2);  // 393216
    int idx = blockIdx.x * blockDim.x + threadIdx.x;
    if (idx >= ITEMS) return;

    int dp  = idx % 48;          // d-pair index, d = 2*dp
    int r1  = idx / 48;
    int m   = r1 % NW;
    int r2  = r1 / NW;
    int n   = r2 % NH;
    int bc  = r2 / NH;           // b*CH + c, 0..31

    // DCT-II matrix for N=6, orthonormal (row 0 scaled by 1/sqrt(2)).
    // M[k][n] = sqrt(2/6)*cos(pi*(2n+1)*k/12), M[0][*] *= 1/sqrt(2).
    constexpr float M[6][6] = {
        { 0.40824829046386302f,  0.40824829046386302f,  0.40824829046386302f,
          0.40824829046386302f,  0.40824829046386302f,  0.40824829046386302f },
        { 0.55767753582520526f,  0.40824829046386302f,  0.14942924536134225f,
         -0.14942924536134225f, -0.40824829046386302f, -0.55767753582520526f },
        { 0.50000000000000000f,  0.00000000000000000f, -0.50000000000000000f,
         -0.50000000000000000f,  0.00000000000000000f,  0.50000000000000000f },
        { 0.40824829046386302f, -0.40824829046386302f, -0.40824829046386302f,
          0.40824829046386302f,  0.40824829046386302f, -0.40824829046386302f },
        { 0.28867513459481292f, -0.57735026918962573f,  0.28867513459481292f,
          0.28867513459481292f, -0.57735026918962573f,  0.28867513459481292f },
        { 0.14942924536134225f, -0.40824829046386302f,  0.55767753582520526f,
         -0.55767753582520526f,  0.40824829046386302f, -0.14942924536134225f },
    };

    // Base offset (in floats) of (bc, n*6, m*6, 2*dp). Max ~28.3M floats -> int ok.
    const int base = ((bc * HH + n * 6) * WW + m * 6) * DD + 2 * dp;
    constexpr int SI = WW * DD;  // stride along i (h) in floats
    constexpr int SJ = DD;       // stride along j (w) in floats

    // Load the 6x6 patch (float2 along D).
    float2 t[6][6];
#pragma unroll
    for (int i = 0; i < 6; ++i) {
#pragma unroll
        for (int j = 0; j < 6; ++j) {
            t[i][j] = *reinterpret_cast<const float2*>(x + base + i * SI + j * SJ);
        }
    }

    // out_row(a) = M[a][:] . t  (over i), then out[a][u] = tmp . M[u][:] (over j)
#pragma unroll
    for (int a = 0; a < 6; ++a) {
        float2 tmp[6];
#pragma unroll
        for (int j = 0; j < 6; ++j) {
            float sx = 0.f, sy = 0.f;
#pragma unroll
            for (int i = 0; i < 6; ++i) {
                sx = fmaf(M[a][i], t[i][j].x, sx);
                sy = fmaf(M[a][i], t[i][j].y, sy);
            }
            tmp[j] = make_float2(sx, sy);
        }
#pragma unroll
        for (int u = 0; u < 6; ++u) {
            float ox = 0.f, oy = 0.f;
#pragma unroll
            for (int j = 0; j < 6; ++j) {
                ox = fmaf(M[u][j], tmp[j].x, ox);
                oy = fmaf(M[u][j], tmp[j].y, oy);
            }
            *reinterpret_cast<float2*>(out + base + a * SI + u * SJ) = make_float2(ox, oy);
        }
    }
}

extern "C" void kernel_launch(void* const* d_in, const int* in_sizes, int n_in,
                              void* d_out, int out_size, void* d_ws, size_t ws_size,
                              hipStream_t stream) {
    const float* x = (const float*)d_in[0];
    float* out = (float*)d_out;
    constexpr int ITEMS = BATCH * CH * NH * NW * (DD / 2);  // 393216
    constexpr int BLOCK = 256;
    constexpr int GRID = (ITEMS + BLOCK - 1) / BLOCK;       // 1536
    dct_patch_kernel<<<GRID, BLOCK, 0, stream>>>(x, out);
}

// Round 2
// 37.776 us; speedup vs baseline: 1.0214x; 1.0214x over previous
//
#include <hip/hip_runtime.h>

// VolumeDCTPatchLayer: per-patch 6x6 2D DCT over (H,W), independent along B,C,D.
// x: (4, 8, 96, 96, 96) f32, contiguous, D innermost.
// out[b,c, n*6+a, m*6+u, d] = sum_{i,j} M[a][i]*M[u][j] * x[b,c, n*6+i, m*6+j, d]
//
// One thread = one (b,c,n,m, d-quad): 16 B/lane float4 loads/stores (m13 copy idiom).

#define BATCH 4
#define CH    8
#define HH    96
#define WW    96
#define DD    96
#define NH    16
#define NW    16

__global__ __launch_bounds__(256) void
dct_patch_kernel(const float* __restrict__ x, float* __restrict__ out) {
    constexpr int QUADS = DD / 4;                       // 24
    constexpr int ITEMS = BATCH * CH * NH * NW * QUADS; // 196608
    int idx = blockIdx.x * blockDim.x + threadIdx.x;
    if (idx >= ITEMS) return;

    int dq  = idx % QUADS;       // d-quad index, d = 4*dq
    int r1  = idx / QUADS;
    int m   = r1 % NW;
    int r2  = r1 / NW;
    int n   = r2 % NH;
    int bc  = r2 / NH;           // b*CH + c, 0..31

    // Orthonormal DCT-II matrix for N=6.
    constexpr float M[6][6] = {
        { 0.40824829046386302f,  0.40824829046386302f,  0.40824829046386302f,
          0.40824829046386302f,  0.40824829046386302f,  0.40824829046386302f },
        { 0.55767753582520526f,  0.40824829046386302f,  0.14942924536134225f,
         -0.14942924536134225f, -0.40824829046386302f, -0.55767753582520526f },
        { 0.50000000000000000f,  0.00000000000000000f, -0.50000000000000000f,
         -0.50000000000000000f,  0.00000000000000000f,  0.50000000000000000f },
        { 0.40824829046386302f, -0.40824829046386302f, -0.40824829046386302f,
          0.40824829046386302f,  0.40824829046386302f, -0.40824829046386302f },
        { 0.28867513459481292f, -0.57735026918962573f,  0.28867513459481292f,
          0.28867513459481292f, -0.57735026918962573f,  0.28867513459481292f },
        { 0.14942924536134225f, -0.40824829046386302f,  0.55767753582520526f,
         -0.55767753582520526f,  0.40824829046386302f, -0.14942924536134225f },
    };

    const int base = ((bc * HH + n * 6) * WW + m * 6) * DD + 4 * dq;  // 16B-aligned
    constexpr int SI = WW * DD;  // stride along i (h) in floats
    constexpr int SJ = DD;       // stride along j (w) in floats

    // Load the full 6x6 patch (float4 along D) — 36 independent 16B loads.
    float4 t[6][6];
#pragma unroll
    for (int i = 0; i < 6; ++i) {
#pragma unroll
        for (int j = 0; j < 6; ++j) {
            t[i][j] = *reinterpret_cast<const float4*>(x + base + i * SI + j * SJ);
        }
    }

    // Row transform then column transform; store each output row immediately.
#pragma unroll
    for (int a = 0; a < 6; ++a) {
        float4 tmp[6];
#pragma unroll
        for (int j = 0; j < 6; ++j) {
            float sx = 0.f, sy = 0.f, sz = 0.f, sw = 0.f;
#pragma unroll
            for (int i = 0; i < 6; ++i) {
                sx = fmaf(M[a][i], t[i][j].x, sx);
                sy = fmaf(M[a][i], t[i][j].y, sy);
                sz = fmaf(M[a][i], t[i][j].z, sz);
                sw = fmaf(M[a][i], t[i][j].w, sw);
            }
            tmp[j] = make_float4(sx, sy, sz, sw);
        }
#pragma unroll
        for (int u = 0; u < 6; ++u) {
            float ox = 0.f, oy = 0.f, oz = 0.f, ow = 0.f;
#pragma unroll
            for (int j = 0; j < 6; ++j) {
                ox = fmaf(M[u][j], tmp[j].x, ox);
                oy = fmaf(M[u][j], tmp[j].y, oy);
                oz = fmaf(M[u][j], tmp[j].z, oz);
                ow = fmaf(M[u][j], tmp[j].w, ow);
            }
            *reinterpret_cast<float4*>(out + base + a * SI + u * SJ) =
                make_float4(ox, oy, oz, ow);
        }
    }
}

extern "C" void kernel_launch(void* const* d_in, const int* in_sizes, int n_in,
                              void* d_out, int out_size, void* d_ws, size_t ws_size,
                              hipStream_t stream) {
    const float* x = (const float*)d_in[0];
    float* out = (float*)d_out;
    constexpr int ITEMS = BATCH * CH * NH * NW * (DD / 4);  // 196608
    constexpr int BLOCK = 256;
    constexpr int GRID = (ITEMS + BLOCK - 1) / BLOCK;       // 768
    dct_patch_kernel<<<GRID, BLOCK, 0, stream>>>(x, out);
}

// Round 4
// 37.631 us; speedup vs baseline: 1.0254x; 1.0039x over previous
//
#include <hip/hip_runtime.h>

// VolumeDCTPatchLayer: per-patch 6x6 2D DCT over (H,W), independent along B,C,D.
// x: (4, 8, 96, 96, 96) f32, contiguous, D innermost.
// out[b,c, n*6+a, m*6+u, d] = sum_{i,j} M[a][i]*M[u][j] * x[b,c, n*6+i, m*6+j, d]
//
// One thread = one (b,c,n,m, d-quad): 16 B/lane float4 loads/stores.
// Stores are NON-TEMPORAL (global_store_dwordx4 ... nt): output is
// write-once/never-read, so keep it out of L2/L3 -> the 113 MB input stays
// L3-resident across graph replays and HBM carries mostly the write stream.

#define BATCH 4
#define CH    8
#define HH    96
#define WW    96
#define DD    96
#define NH    16
#define NW    16

typedef float f32x4 __attribute__((ext_vector_type(4)));

__global__ __launch_bounds__(256) void
dct_patch_kernel(const float* __restrict__ x, float* __restrict__ out) {
    constexpr int QUADS = DD / 4;                       // 24
    constexpr int ITEMS = BATCH * CH * NH * NW * QUADS; // 196608
    int idx = blockIdx.x * blockDim.x + threadIdx.x;
    if (idx >= ITEMS) return;

    int dq  = idx % QUADS;       // d-quad index, d = 4*dq
    int r1  = idx / QUADS;
    int m   = r1 % NW;
    int r2  = r1 / NW;
    int n   = r2 % NH;
    int bc  = r2 / NH;           // b*CH + c, 0..31

    // Orthonormal DCT-II matrix for N=6.
    constexpr float M[6][6] = {
        { 0.40824829046386302f,  0.40824829046386302f,  0.40824829046386302f,
          0.40824829046386302f,  0.40824829046386302f,  0.40824829046386302f },
        { 0.55767753582520526f,  0.40824829046386302f,  0.14942924536134225f,
         -0.14942924536134225f, -0.40824829046386302f, -0.55767753582520526f },
        { 0.50000000000000000f,  0.00000000000000000f, -0.50000000000000000f,
         -0.50000000000000000f,  0.00000000000000000f,  0.50000000000000000f },
        { 0.40824829046386302f, -0.40824829046386302f, -0.40824829046386302f,
          0.40824829046386302f,  0.40824829046386302f, -0.40824829046386302f },
        { 0.28867513459481292f, -0.57735026918962573f,  0.28867513459481292f,
          0.28867513459481292f, -0.57735026918962573f,  0.28867513459481292f },
        { 0.14942924536134225f, -0.40824829046386302f,  0.55767753582520526f,
         -0.55767753582520526f,  0.40824829046386302f, -0.14942924536134225f },
    };

    const int base = ((bc * HH + n * 6) * WW + m * 6) * DD + 4 * dq;  // 16B-aligned
    constexpr int SI = WW * DD;  // stride along i (h) in floats
    constexpr int SJ = DD;       // stride along j (w) in floats

    // Load the full 6x6 patch (f32x4 along D) — 36 independent 16B loads.
    f32x4 t[6][6];
#pragma unroll
    for (int i = 0; i < 6; ++i) {
#pragma unroll
        for (int j = 0; j < 6; ++j) {
            t[i][j] = *reinterpret_cast<const f32x4*>(x + base + i * SI + j * SJ);
        }
    }

    // Row transform then column transform; store each output row immediately.
#pragma unroll
    for (int a = 0; a < 6; ++a) {
        f32x4 tmp[6];
#pragma unroll
        for (int j = 0; j < 6; ++j) {
            f32x4 s = (f32x4)(0.f);
#pragma unroll
            for (int i = 0; i < 6; ++i) {
                s += M[a][i] * t[i][j];
            }
            tmp[j] = s;
        }
#pragma unroll
        for (int u = 0; u < 6; ++u) {
            f32x4 o = (f32x4)(0.f);
#pragma unroll
            for (int j = 0; j < 6; ++j) {
                o += M[u][j] * tmp[j];
            }
            __builtin_nontemporal_store(
                o, reinterpret_cast<f32x4*>(out + base + a * SI + u * SJ));
        }
    }
}

extern "C" void kernel_launch(void* const* d_in, const int* in_sizes, int n_in,
                              void* d_out, int out_size, void* d_ws, size_t ws_size,
                              hipStream_t stream) {
    const float* x = (const float*)d_in[0];
    float* out = (float*)d_out;
    constexpr int ITEMS = BATCH * CH * NH * NW * (DD / 4);  // 196608
    constexpr int BLOCK = 256;
    constexpr int GRID = (ITEMS + BLOCK - 1) / BLOCK;       // 768
    dct_patch_kernel<<<GRID, BLOCK, 0, stream>>>(x, out);
}